// Round 2
// baseline (263.585 us; speedup 1.0000x reference)
//
#include <hip/hip_runtime.h>
#include <stdint.h>

// Problem constants (fixed by reference):
//   N=16384 spatial, R=16 feat, P=4096 blocks, T=64 out-feat, B=8 batch
#define C_N 16384
#define C_R 16
#define C_P 4096
#define C_B 8

// R1 restructure: weights never touch LDS. One wave per (p, half):
//   lane = output column o (0..63), all 8 batch accumulators in VGPRs.
//   Weights streamed global->register (coalesced 256 B rows), hand-
//   pipelined depth 2 (named buffers, all indices compile-time).
// Only the 4 KB x tile is staged in LDS (shared by both halves in a
// 128-thread WG); the single barrier waits on 4 KB, not 36 KB, and the
// hot loop has NO barrier -> waves stream independently, HBM demand is
// continuous instead of convoy-phased. LDS traffic drops ~30x.
__global__ __launch_bounds__(128)
void butterfly_local_conv(const float* __restrict__ x,
                          const float* __restrict__ Wrr,
                          const float* __restrict__ Wri,
                          const float* __restrict__ Wir,
                          const float* __restrict__ Wii,
                          const int*   __restrict__ perm,
                          float* __restrict__ out)
{
    __shared__ float xs[2][C_B][64];   // 4 KB: [c][b][i], i = s*16 + r

    const int t    = threadIdx.x;
    const int lane = t & 63;
    const int half = t >> 6;           // wave 0 -> y_re, wave 1 -> y_im
    const int p    = blockIdx.x;

    // ---- cooperative x staging: 2 float4 per thread (256 float4 total)
    #pragma unroll
    for (int j = 0; j < 2; ++j) {
        const int idx = t * 2 + j;             // 0..255
        const int c = idx >> 7;                // re/im component of x
        const int b = (idx >> 4) & 7;          // batch
        const int s = (idx >> 2) & 3;          // window position
        const int q = idx & 3;                 // float4 within row of 16
        const int n = perm[4 * p + s];
        const float4 v =
            ((const float4*)(x + (((size_t)(b * 2 + c)) * C_N + n) * C_R))[q];
        *(float4*)&xs[c][b][s * 16 + q * 4] = v;
    }
    __syncthreads();

    // ---- weight streaming pointers for this wave's half
    const float* __restrict__ WA = (half ? Wir : Wrr) + (size_t)p * 4096 + lane;
    const float* __restrict__ WB = (half ? Wii : Wri) + (size_t)p * 4096 + lane;

    float acc[C_B] = {0.f, 0.f, 0.f, 0.f, 0.f, 0.f, 0.f, 0.f};

// load 4 weight rows (i = cc*4 .. cc*4+3) of both matrices into named regs
#define LOADC(A, Bv, cc)                                     \
    _Pragma("unroll")                                        \
    for (int k = 0; k < 4; ++k) {                            \
        A[k]  = WA[((cc) * 4 + k) * 64];                     \
        Bv[k] = WB[((cc) * 4 + k) * 64];                     \
    }

// consume 4 rows: per batch, 2 broadcast ds_read_b128 of x + 8 FMAs
#define COMPC(A, Bv, cc)                                     \
    _Pragma("unroll")                                        \
    for (int b = 0; b < C_B; ++b) {                          \
        const float4 xr = *(const float4*)&xs[0][b][(cc)*4]; \
        const float4 xi = *(const float4*)&xs[1][b][(cc)*4]; \
        acc[b] = fmaf(xr.x, A[0],  acc[b]);                  \
        acc[b] = fmaf(xi.x, Bv[0], acc[b]);                  \
        acc[b] = fmaf(xr.y, A[1],  acc[b]);                  \
        acc[b] = fmaf(xi.y, Bv[1], acc[b]);                  \
        acc[b] = fmaf(xr.z, A[2],  acc[b]);                  \
        acc[b] = fmaf(xi.z, Bv[2], acc[b]);                  \
        acc[b] = fmaf(xr.w, A[3],  acc[b]);                  \
        acc[b] = fmaf(xi.w, Bv[3], acc[b]);                  \
    }

    // ---- depth-2 software pipeline over 16 chunks of 4 rows.
    // Fully unrolled: every buffer index is compile-time (no scratch).
    float wa0[4], wb0[4], wa1[4], wb1[4];
    LOADC(wa0, wb0, 0);
    #pragma unroll
    for (int c = 0; c < 16; c += 2) {
        LOADC(wa1, wb1, c + 1);        // prefetch odd chunk
        COMPC(wa0, wb0, c);            // compute even chunk
        if (c + 2 < 16) { LOADC(wa0, wb0, c + 2); }  // prefetch next even
        COMPC(wa1, wb1, c + 1);        // compute odd chunk
    }
#undef LOADC
#undef COMPC

    // ---- store: 8 coalesced 256 B stores per wave
    const size_t obase = (size_t)p * 64 + lane;
    #pragma unroll
    for (int b = 0; b < C_B; ++b) {
        out[((size_t)(b * 2 + half)) * (C_N * C_R) + obase] = acc[b];
    }
}

extern "C" void kernel_launch(void* const* d_in, const int* in_sizes, int n_in,
                              void* d_out, int out_size, void* d_ws, size_t ws_size,
                              hipStream_t stream) {
    const float* x    = (const float*)d_in[0];
    const float* Wrr  = (const float*)d_in[1];
    const float* Wri  = (const float*)d_in[2];
    const float* Wir  = (const float*)d_in[3];
    const float* Wii  = (const float*)d_in[4];
    const int*   perm = (const int*)d_in[5];
    float* out = (float*)d_out;

    // One 128-thread WG (2 waves: re half, im half) per block p.
    butterfly_local_conv<<<dim3(C_P), dim3(128), 0, stream>>>(
        x, Wrr, Wri, Wir, Wii, perm, out);
}